// Round 7
// baseline (257.229 us; speedup 1.0000x reference)
//
#include <hip/hip_runtime.h>

#define DEVI __device__ __forceinline__

typedef _Float16 f16x8 __attribute__((ext_vector_type(8)));
typedef _Float16 f16x4v __attribute__((ext_vector_type(4)));
typedef _Float16 f16x2 __attribute__((ext_vector_type(2)));
typedef __fp16 fp16x2 __attribute__((ext_vector_type(2)));
typedef float f32x4 __attribute__((ext_vector_type(4)));
typedef float f32x16 __attribute__((ext_vector_type(16)));
typedef unsigned u32x4 __attribute__((ext_vector_type(4)));

DEVI void gl16(const void* g, void* l) {
  __builtin_amdgcn_global_load_lds((const __attribute__((address_space(1))) void*)g,
                                   (__attribute__((address_space(3))) void*)l, 16, 0, 0);
}

#define VMCNT(N) asm volatile("s_waitcnt vmcnt(" #N ")" ::: "memory")
#define LGKM0() asm volatile("s_waitcnt lgkmcnt(0)" ::: "memory")
#define BARRIER() asm volatile("s_barrier" ::: "memory")

DEVI unsigned pk2(float a, float b) {
  fp16x2 t = __builtin_amdgcn_cvt_pkrtz(a, b);
  return __builtin_bit_cast(unsigned, t);
}
DEVI void pl32swap(unsigned &a, unsigned &b) {
  asm volatile("v_permlane32_swap_b32 %0, %1" : "+v"(a), "+v"(b));
}

// ---------------- fused prep: x f32->f16 + both weight transposes ----------------
__global__ __launch_bounds__(256) void k_prep(const float* __restrict__ x, _Float16* __restrict__ xb,
                                              const float* __restrict__ w_in, _Float16* __restrict__ w_inT,
                                              const float* __restrict__ w_out, _Float16* __restrict__ w_outT) {
  __shared__ float t[32][33];
  int bid = blockIdx.x;
  int tid = threadIdx.x;
  if (bid < 2048) {
    const int n4 = 8192 * 1280 / 4;
    for (int i = bid * 256 + tid; i < n4; i += 2048 * 256) {
      float4 v = ((const float4*)x)[i];
      f16x4v h = { (_Float16)v.x, (_Float16)v.y, (_Float16)v.z, (_Float16)v.w };
      ((f16x4v*)xb)[i] = h;
    }
    return;
  }
  const float* in; _Float16* out; int R, C, tIdx;
  if (bid < 6848) { in = w_in;  out = w_inT;  R = 1280; C = 3840; tIdx = bid - 2048; }
  else            { in = w_out; out = w_outT; R = 1280; C = 1280; tIdx = bid - 6848; }
  int ntc = C / 32;
  int cb = (tIdx % ntc) * 32, rb = (tIdx / ntc) * 32;
  int tx = tid & 31, ty = tid >> 5;
  #pragma unroll
  for (int i = ty; i < 32; i += 8) t[i][tx] = in[(size_t)(rb + i) * C + cb + tx];
  __syncthreads();
  #pragma unroll
  for (int i = ty; i < 32; i += 8) out[(size_t)(cb + i) * R + rb + tx] = (_Float16)t[tx][i];
}

// ================= 256x256 8-phase GEMM (qkv producer), B triple-buffered =================
// LDS 160 KiB: A = 2 par x 2 hh x [128][64] f16 (64 KB), B = 3 slots x [256][64] f16 (96 KB).
// One half-tile stage (2 x global_load_lds) per phase -> prefetch lead: B 6-8 phases (covers L3),
// A 4-6 phases (covers L2). Counted VMCNT(6) at ph3/ph7 only.

#define MM(NLO, AF, BF) do {                                                                       \
    __builtin_amdgcn_s_setprio(1);                                                                 \
    _Pragma("unroll")                                                                              \
    for (int m_ = 0; m_ < 8; m_++) {                                                               \
      acc[m_][NLO]     = __builtin_amdgcn_mfma_f32_16x16x32_f16(AF[m_], BF[NLO],     acc[m_][NLO],     0, 0, 0); \
      acc[m_][NLO + 1] = __builtin_amdgcn_mfma_f32_16x16x32_f16(AF[m_], BF[NLO + 1], acc[m_][NLO + 1], 0, 0, 0); \
    }                                                                                              \
    __builtin_amdgcn_s_setprio(0);                                                                 \
  } while (0)

#define LDA(KT, KK, DST) do {                                                                      \
    const _Float16* bas_ = &smem[(size_t)((((KT) & 1) * 2) + wr) * 8192];                          \
    _Pragma("unroll")                                                                              \
    for (int m_ = 0; m_ < 8; m_++)                                                                 \
      DST[m_] = *(const f16x8*)&bas_[(m_ * 16 + ln) * 64 + (((((KK) * 4) + g) ^ chB) << 3)];       \
  } while (0)

#define LDB(SLOT, KK, DST) do {                                                                    \
    const _Float16* bas_ = &smem[32768 + (size_t)(SLOT) * 16384 + (size_t)(wc >> 1) * 8192];       \
    _Pragma("unroll")                                                                              \
    for (int n_ = 0; n_ < 4; n_++)                                                                 \
      DST[n_] = *(const f16x8*)&bas_[((wc & 1) * 64 + n_ * 16 + ln) * 64 + (((((KK) * 4) + g) ^ chB) << 3)]; \
  } while (0)

template<int M, int N, int K>
__global__ __launch_bounds__(512, 2) void k_gemm8(const _Float16* __restrict__ A, const _Float16* __restrict__ BT,
                                                  const float* __restrict__ bias,
                                                  _Float16* __restrict__ qo, _Float16* __restrict__ ko,
                                                  _Float16* __restrict__ vo) {
  extern __shared__ _Float16 smem[];
  constexpr int NT = K / 64;
  constexpr int NI = NT / 2;
  const int tid = threadIdx.x;
  const int w = tid >> 6, lane = tid & 63, ln = lane & 15, g = lane >> 4;
  const int wr = w >> 2, wc = w & 3;
  const int l8 = lane >> 3, l7 = lane & 7;
  const int stChunk = (l7 ^ l8) << 3;
  const int chB = ln & 7;

  constexpr int MT = M / 256;
  const int xcd = blockIdx.x & 7;
  const int i = blockIdx.x >> 3;
  const int bm0 = (xcd * (MT / 8) + (i & 3)) * 256;
  const int bn0 = (i >> 2) * 256;

  auto stgA = [&](int kt, int hh) {
    _Float16* ldsb = &smem[(size_t)((kt & 1) * 2 + hh) * 8192 + w * 1024];
    const _Float16* g0 = &A[(size_t)(bm0 + hh * 128 + w * 16 + l8) * K + kt * 64 + stChunk];
    gl16(g0, ldsb);
    gl16(g0 + (size_t)8 * K, ldsb + 512);
  };
  auto stgB = [&](int slot, int kt, int hh) {
    _Float16* ldsb = &smem[32768 + (size_t)slot * 16384 + (size_t)hh * 8192 + w * 1024];
    const _Float16* g0 = &BT[(size_t)(bn0 + hh * 128 + w * 16 + l8) * K + kt * 64 + stChunk];
    gl16(g0, ldsb);
    gl16(g0 + (size_t)8 * K, ldsb + 512);
  };

  f32x4 acc[8][4] = {};
  f16x8 a0[8], a1[8], b0[4], b1[4];

  // prologue: B(0)->slot0, B(1)->slot1, A(0), A(1)   (16 loads)
  stgB(0, 0, 0); stgB(0, 0, 1); stgB(1, 1, 0); stgB(1, 1, 1);
  stgA(0, 0); stgA(0, 1); stgA(1, 0); stgA(1, 1);
  VMCNT(4);         // B(0),B(1),A(0) landed; A(1) may be in flight
  BARRIER();
  LDA(0, 0, a0); LDB(0, 0, b0);

  for (int it = 0; it < NI; ++it) {
    const int T0 = 2 * it, T1 = 2 * it + 1;
    const int S0w = (T0 + 2 < NT) ? T0 + 2 : 0;   // wrapped data index (tail data never read)
    const int S1w = (T1 + 2 < NT) ? T1 + 2 : 1;
    const int sT0 = T0 % 3;
    const int sT1 = (sT0 + 1 == 3) ? 0 : sT0 + 1;
    const int sS0 = (sT1 + 1 == 3) ? 0 : sT1 + 1;
    const int sS1 = sT0;
    // ph1
    LDB(sT0, 1, b1);
    stgB(sS0, S0w, 0);
    BARRIER(); MM(0, a0, b0); LGKM0(); BARRIER();
    // ph2
    LDA(T0, 1, a1);
    stgB(sS0, S0w, 1);
    BARRIER(); MM(2, a0, b0); LGKM0(); BARRIER();
    // ph3
    stgA(S0w, 0);
    BARRIER(); MM(0, a1, b1); VMCNT(6); LGKM0(); BARRIER();
    // ph4
    LDA(T1, 0, a0); LDB(sT1, 0, b0);
    stgA(S0w, 1);
    BARRIER(); MM(2, a1, b1); LGKM0(); BARRIER();
    // ph5
    LDB(sT1, 1, b1);
    stgB(sS1, S1w, 0);
    BARRIER(); MM(0, a0, b0); LGKM0(); BARRIER();
    // ph6
    LDA(T1, 1, a1);
    stgB(sS1, S1w, 1);
    BARRIER(); MM(2, a0, b0); LGKM0(); BARRIER();
    // ph7
    stgA(S1w, 0);
    BARRIER(); MM(0, a1, b1); VMCNT(6); LGKM0(); BARRIER();
    // ph8
    LDA(S0w, 0, a0); LDB(sS0, 0, b0);
    stgA(S1w, 1);
    BARRIER(); MM(2, a1, b1); LGKM0(); BARRIER();
  }

  // epilogue: acc -> LDS f16 [256][256] -> coalesced 16B q/k/v stores
  VMCNT(0);
  BARRIER();
  _Float16* sH = smem;
  #pragma unroll
  for (int n = 0; n < 4; n++) {
    int col = wc * 64 + n * 16 + ln;
    int gcol = bn0 + col;
    float bv = bias[gcol];
    int hq = gcol / 240;
    int tt = gcol - hq * 240;
    // q gets 1/sqrt(80) * log2(e) so attention works in exp2 domain
    float scl = (tt < 80) ? (0.11180339887498948f * 1.4426950408889634f) : 1.0f;
    #pragma unroll
    for (int m = 0; m < 8; m++) {
      #pragma unroll
      for (int r = 0; r < 4; r++) {
        int row = wr * 128 + m * 16 + 4 * g + r;
        sH[row * 256 + col] = (_Float16)((acc[m][n][r] + bv) * scl);
      }
    }
  }
  LGKM0();
  BARRIER();
  #pragma unroll
  for (int i2 = 0; i2 < 16; i2++) {
    int id = tid + 512 * i2;
    int row = id >> 5, c8 = id & 31;
    f16x8 v = *(const f16x8*)&sH[row * 256 + c8 * 8];
    int gcol = bn0 + c8 * 8;
    int grow = bm0 + row;
    int hq = gcol / 240;
    int tt = gcol - hq * 240;
    int reg = tt / 80;
    int cc = tt - reg * 80;
    int s = grow >> 3;
    int head = (grow & 7) * 16 + hq;
    _Float16* dst = (reg == 0) ? qo : (reg == 1) ? ko : vo;
    *(f16x8*)&dst[(size_t)(head * 1024 + s) * 80 + cc] = v;
  }
}

// ---------------- 128x128 GEMM (out_proj) ----------------
template<int M, int N, int K>
__global__ __launch_bounds__(256) void k_gemm(const _Float16* __restrict__ A, const _Float16* __restrict__ BT,
                                              const float* __restrict__ bias, float* __restrict__ outF) {
  __shared__ _Float16 Al[128 * 32];
  __shared__ _Float16 Bl[128 * 32];
  const int tid = threadIdx.x;
  const int w = tid >> 6, lane = tid & 63, ln = lane & 15, g = lane >> 4;
  const int bm0 = blockIdx.x * 128, bn0 = blockIdx.y * 128;
  const int wm = (w >> 1) * 64, wn = (w & 1) * 64;
  const int r0 = tid >> 2, c0 = (tid & 3) * 8;
  f32x4 acc[4][4] = {};
  for (int kt = 0; kt < K; kt += 32) {
    __syncthreads();
    gl16(&A[(size_t)(bm0 + r0) * K + kt + c0],      &Al[(w * 64) * 8]);
    gl16(&A[(size_t)(bm0 + r0 + 64) * K + kt + c0], &Al[(256 + w * 64) * 8]);
    gl16(&BT[(size_t)(bn0 + r0) * K + kt + c0],      &Bl[(w * 64) * 8]);
    gl16(&BT[(size_t)(bn0 + r0 + 64) * K + kt + c0], &Bl[(256 + w * 64) * 8]);
    __syncthreads();
    f16x8 af[4], bf[4];
    #pragma unroll
    for (int i = 0; i < 4; i++) af[i] = *(const f16x8*)&Al[(wm + i * 16 + ln) * 32 + g * 8];
    #pragma unroll
    for (int i = 0; i < 4; i++) bf[i] = *(const f16x8*)&Bl[(wn + i * 16 + ln) * 32 + g * 8];
    #pragma unroll
    for (int i = 0; i < 4; i++)
      #pragma unroll
      for (int j = 0; j < 4; j++)
        acc[i][j] = __builtin_amdgcn_mfma_f32_16x16x32_f16(af[i], bf[j], acc[i][j], 0, 0, 0);
  }
  #pragma unroll
  for (int j = 0; j < 4; j++) {
    int col = bn0 + wn + j * 16 + ln;
    float bv = bias[col];
    #pragma unroll
    for (int i = 0; i < 4; i++) {
      int mb = bm0 + wm + i * 16 + 4 * g;
      #pragma unroll
      for (int r = 0; r < 4; r++)
        outF[(size_t)(mb + r) * N + col] = acc[i][j][r] + bv;
    }
  }
}

// ---------------- per-head V transpose ----------------
__global__ __launch_bounds__(256) void k_vtrans(const _Float16* __restrict__ vb, _Float16* __restrict__ vT) {
  __shared__ _Float16 t[64][81];
  int head = blockIdx.x >> 4;
  int sb = (blockIdx.x & 15) * 64;
  for (int idx = threadIdx.x; idx < 64 * 80; idx += 256) {
    int s = idx / 80, d = idx - s * 80;
    t[s][d] = vb[(head * 1024 + sb + s) * 80 + d];
  }
  __syncthreads();
  for (int idx = threadIdx.x; idx < 80 * 64; idx += 256) {
    int d = idx >> 6, s = idx & 63;
    vT[(head * 80 + d) * 1024 + sb + s] = t[s][d];
  }
}

// ---------------- flash attention: QBLK=256, 8 waves x 32 q-rows, in-register softmax ----------------
__global__ __launch_bounds__(512, 2) void k_attn(const _Float16* __restrict__ qb, const _Float16* __restrict__ kb,
                                                 const _Float16* __restrict__ vT, _Float16* __restrict__ ctxg) {
  extern __shared__ _Float16 smem[];
  _Float16* Kb0 = smem;                    // [64][128]
  _Float16* Kb1 = smem + 8192;
  _Float16* Vb0 = smem + 16384;            // [96][64]; rows 80..95 never written/stored
  _Float16* Vb1 = smem + 16384 + 6144;

  const int tid = threadIdx.x;
  const int w = tid >> 6, lane = tid & 63;
  const int l32 = lane & 31, h = lane >> 5;
  const int lx = l32 & 7;
  const int xcd = blockIdx.x & 7;
  const int j = blockIdx.x >> 3;
  const int head = xcd + 8 * (j & 15);
  const int s0 = (j >> 4) * 256;
  const int bb = head >> 4, h16 = head & 15;

  const int c1 = (tid < 128) ? tid + 512 : tid;
  const int kr0 = tid / 10, kh0 = tid - kr0 * 10;
  const int kr1 = c1 / 10,  kh1 = c1 - kr1 * 10;
  const int vr0 = tid >> 3, vh0 = tid & 7;
  const int vr1 = c1 >> 3,  vh1 = c1 & 7;
  const int kO0 = kr0 * 128 + ((kh0 ^ (kr0 & 7)) << 3);
  const int kO1 = kr1 * 128 + ((kh1 ^ (kr1 & 7)) << 3);
  const int vO0 = vr0 * 64 + ((vh0 ^ (vr0 & 7)) << 3);
  const int vO1 = vr1 * 64 + ((vh1 ^ (vr1 & 7)) << 3);
  const _Float16* kG0 = kb + (size_t)head * 81920 + kr0 * 80 + kh0 * 8;
  const _Float16* kG1 = kb + (size_t)head * 81920 + kr1 * 80 + kh1 * 8;
  const _Float16* vG0 = vT + (size_t)head * 81920 + vr0 * 1024 + vh0 * 8;
  const _Float16* vG1 = vT + (size_t)head * 81920 + vr1 * 1024 + vh1 * 8;

  uint4 krA, krB, vrA, vrB;
  auto issue = [&](int kt) {
    krA = *(const uint4*)(kG0 + kt * 5120);
    krB = *(const uint4*)(kG1 + kt * 5120);
    vrA = *(const uint4*)(vG0 + kt * 64);
    vrB = *(const uint4*)(vG1 + kt * 64);
  };
  auto stage = [&](int b) {
    _Float16* kd = b ? Kb1 : Kb0;
    _Float16* vd = b ? Vb1 : Vb0;
    *(uint4*)(kd + kO0) = krA;
    *(uint4*)(kd + kO1) = krB;
    *(uint4*)(vd + vO0) = vrA;
    *(uint4*)(vd + vO1) = vrB;
  };

  const int qrow = s0 + w * 32 + l32;
  f16x8 qf[5];
  #pragma unroll
  for (int s = 0; s < 5; s++)
    qf[s] = *(const f16x8*)&qb[(size_t)(head * 1024 + qrow) * 80 + s * 16 + h * 8];

  f32x16 ct[3] = {};
  float m_run = -INFINITY, l_run = 0.f;

  issue(0);
  stage(0);
  LGKM0();
  BARRIER();
  issue(1);

  for (int kt = 0; kt < 16; ++kt) {
    const _Float16* kc = (kt & 1) ? Kb1 : Kb0;
    const _Float16* vc = (kt & 1) ? Vb1 : Vb0;

    f32x16 sc0 = {}, sc1 = {};
    __builtin_amdgcn_s_setprio(1);
    #pragma unroll
    for (int s = 0; s < 5; ++s) {
      f16x8 kf0 = *(const f16x8*)&kc[l32 * 128 + (((2 * s + h) ^ lx) << 3)];
      f16x8 kf1 = *(const f16x8*)&kc[(32 + l32) * 128 + (((2 * s + h) ^ lx) << 3)];
      sc0 = __builtin_amdgcn_mfma_f32_32x32x16_f16(kf0, qf[s], sc0, 0, 0, 0);
      sc1 = __builtin_amdgcn_mfma_f32_32x32x16_f16(kf1, qf[s], sc1, 0, 0, 0);
    }
    __builtin_amdgcn_s_setprio(0);

    float mx[8];
    #pragma unroll
    for (int i = 0; i < 8; ++i)
      mx[i] = fmaxf(fmaxf(sc0[i], sc0[i + 8]), fmaxf(sc1[i], sc1[i + 8]));
    #pragma unroll
    for (int i = 0; i < 4; ++i) mx[i] = fmaxf(mx[i], mx[i + 4]);
    float tm = fmaxf(fmaxf(mx[0], mx[2]), fmaxf(mx[1], mx[3]));
    tm = fmaxf(tm, __shfl_xor(tm, 32));
    float mnew = fmaxf(m_run, tm);
    float fac = exp2f(m_run - mnew);
    float p0[16], p1[16];
    #pragma unroll
    for (int i = 0; i < 16; ++i) p0[i] = exp2f(sc0[i] - mnew);
    #pragma unroll
    for (int i = 0; i < 16; ++i) p1[i] = exp2f(sc1[i] - mnew);
    float ps = 0.f;
    #pragma unroll
    for (int i = 0; i < 16; ++i) ps += p0[i] + p1[i];

    unsigned fr[4][4];
    #define PACK4(T, PP) do {                                                \
        _Pragma("unroll")                                                    \
        for (int s16 = 0; s16 < 2; ++s16) {                                  \
          unsigned u0 = pk2(PP[8 * s16 + 0], PP[8 * s16 + 1]);               \
          unsigned u1 = pk2(PP[8 * s16 + 2], PP[8 * s16 + 3]);               \
          unsigned u2 = pk2(PP[8 * s16 + 4], PP[8 * s16 + 5]);               \
          unsigned u3 = pk2(PP[8 * s16 + 6], PP[8 * s16 + 7]);               \
          pl32swap(u0, u2); pl32swap(u1, u3);                                \
          fr[2 * (T) + s16][0] = u0; fr[2 * (T) + s16][1] = u1;              \
          fr[2 * (T) + s16][2] = u2; fr[2 * (T) + s16][3] = u3;              \
        }                                                                    \
      } while (0)
    PACK4(0, p0);
    PACK4(1, p1);

    l_run = l_run * fac + (ps + __shfl_xor(ps, 32));
    m_run = mnew;

    #pragma unroll
    for (int dt = 0; dt < 3; ++dt)
      #pragma unroll
      for (int i = 0; i < 16; ++i) ct[dt][i] *= fac;

    __builtin_amdgcn_s_setprio(1);
    #pragma unroll
    for (int ss = 0; ss < 4; ++ss) {
      u32x4 fu = { fr[ss][0], fr[ss][1], fr[ss][2], fr[ss][3] };
      f16x8 pf = __builtin_bit_cast(f16x8, fu);
      #pragma unroll
      for (int dt = 0; dt < 3; ++dt) {
        f16x8 vf = *(const f16x8*)&vc[(dt * 32 + l32) * 64 + (((2 * ss + h) ^ lx) << 3)];
        ct[dt] = __builtin_amdgcn_mfma_f32_32x32x16_f16(vf, pf, ct[dt], 0, 0, 0);
      }
    }
    __builtin_amdgcn_s_setprio(0);

    if (kt < 15) {
      stage((kt + 1) & 1);
      LGKM0();
      BARRIER();
      if (kt < 14) issue(kt + 2);
    }
  }

  float inv = 1.f / l_run;
  int sq = s0 + w * 32 + l32;
  _Float16* outp = ctxg + (size_t)(sq * 8 + bb) * 1280 + h16 * 80 + 4 * h;
  #pragma unroll
  for (int dt = 0; dt < 3; ++dt)
    #pragma unroll
    for (int rq = 0; rq < 4; ++rq) {
      if (dt == 2 && rq >= 2) continue;
      f16x4v o = { (_Float16)(ct[dt][rq * 4 + 0] * inv), (_Float16)(ct[dt][rq * 4 + 1] * inv),
                   (_Float16)(ct[dt][rq * 4 + 2] * inv), (_Float16)(ct[dt][rq * 4 + 3] * inv) };
      *(f16x4v*)&outp[dt * 32 + rq * 8] = o;
    }
}

extern "C" void kernel_launch(void* const* d_in, const int* in_sizes, int n_in,
                              void* d_out, int out_size, void* d_ws, size_t ws_size,
                              hipStream_t stream) {
  const float* x     = (const float*)d_in[0];
  const float* w_in  = (const float*)d_in[1];
  const float* b_in  = (const float*)d_in[2];
  const float* w_out = (const float*)d_in[3];
  const float* b_out = (const float*)d_in[4];
  float* out = (float*)d_out;

  char* ws = (char*)d_ws;
  size_t off = 0;
  auto carve = [&](size_t bytes) -> void* {
    void* p = ws + off;
    off += (bytes + 255) & ~(size_t)255;
    return p;
  };
  _Float16* xb     = (_Float16*)carve(8192ull * 1280 * 2);
  _Float16* w_inT  = (_Float16*)carve(3840ull * 1280 * 2);
  _Float16* w_outT = (_Float16*)carve(1280ull * 1280 * 2);
  _Float16* qb     = (_Float16*)carve(128ull * 1024 * 80 * 2);
  _Float16* kbuf   = (_Float16*)carve(128ull * 1024 * 80 * 2);
  _Float16* vb     = (_Float16*)carve(128ull * 1024 * 80 * 2);
  _Float16* vT     = (_Float16*)carve(128ull * 1024 * 80 * 2);
  _Float16* ctxg   = (_Float16*)carve(8192ull * 1280 * 2);
  if (off > ws_size) return;

  hipFuncSetAttribute(reinterpret_cast<const void*>(&k_gemm8<8192, 3840, 1280>),
                      hipFuncAttributeMaxDynamicSharedMemorySize, 163840);
  hipFuncSetAttribute(reinterpret_cast<const void*>(&k_attn),
                      hipFuncAttributeMaxDynamicSharedMemorySize, 57344);

  k_prep<<<8448, 256, 0, stream>>>(x, xb, w_in, w_inT, w_out, w_outT);

  k_gemm8<8192, 3840, 1280><<<480, 512, 163840, stream>>>(xb, w_inT, b_in, qb, kbuf, vb);
  k_vtrans<<<2048, 256, 0, stream>>>(vb, vT);
  k_attn<<<512, 512, 57344, stream>>>(qb, kbuf, vT, ctxg);
  k_gemm<8192, 1280, 1280><<<dim3(64, 10), 256, 0, stream>>>(ctxg, w_outT, b_out, out);
}

// Round 8
// 240.077 us; speedup vs baseline: 1.0714x; 1.0714x over previous
//
#include <hip/hip_runtime.h>

#define DEVI __device__ __forceinline__

typedef _Float16 f16x8 __attribute__((ext_vector_type(8)));
typedef _Float16 f16x4v __attribute__((ext_vector_type(4)));
typedef _Float16 f16x2 __attribute__((ext_vector_type(2)));
typedef __fp16 fp16x2 __attribute__((ext_vector_type(2)));
typedef float f32x4 __attribute__((ext_vector_type(4)));
typedef float f32x16 __attribute__((ext_vector_type(16)));
typedef unsigned u32x4 __attribute__((ext_vector_type(4)));

DEVI void gl16(const void* g, void* l) {
  __builtin_amdgcn_global_load_lds((const __attribute__((address_space(1))) void*)g,
                                   (__attribute__((address_space(3))) void*)l, 16, 0, 0);
}

#define VMCNT(N) asm volatile("s_waitcnt vmcnt(" #N ")" ::: "memory")
#define LGKM0() asm volatile("s_waitcnt lgkmcnt(0)" ::: "memory")
#define BARRIER() asm volatile("s_barrier" ::: "memory")

DEVI unsigned pk2(float a, float b) {
  fp16x2 t = __builtin_amdgcn_cvt_pkrtz(a, b);
  return __builtin_bit_cast(unsigned, t);
}
DEVI void pl32swap(unsigned &a, unsigned &b) {
  asm volatile("v_permlane32_swap_b32 %0, %1" : "+v"(a), "+v"(b));
}

// ---------------- fused prep: x f32->f16 + both weight transposes ----------------
// w_inT columns are PERMUTED: new col = reg*1280 + head*80 + d  (reg 0=q,1=k,2=v)
// so the in_proj GEMM's N axis is [q:1280][k:1280][v:1280].
__global__ __launch_bounds__(256) void k_prep(const float* __restrict__ x, _Float16* __restrict__ xb,
                                              const float* __restrict__ w_in, _Float16* __restrict__ w_inT,
                                              const float* __restrict__ w_out, _Float16* __restrict__ w_outT) {
  __shared__ float t[32][33];
  int bid = blockIdx.x;
  int tid = threadIdx.x;
  if (bid < 2048) {
    const int n4 = 8192 * 1280 / 4;
    for (int i = bid * 256 + tid; i < n4; i += 2048 * 256) {
      float4 v = ((const float4*)x)[i];
      f16x4v h = { (_Float16)v.x, (_Float16)v.y, (_Float16)v.z, (_Float16)v.w };
      ((f16x4v*)xb)[i] = h;
    }
    return;
  }
  const float* in; _Float16* out; int R, C, tIdx; bool perm;
  if (bid < 6848) { in = w_in;  out = w_inT;  R = 1280; C = 3840; tIdx = bid - 2048; perm = true; }
  else            { in = w_out; out = w_outT; R = 1280; C = 1280; tIdx = bid - 6848; perm = false; }
  int ntc = C / 32;
  int cb = (tIdx % ntc) * 32, rb = (tIdx / ntc) * 32;
  int tx = tid & 31, ty = tid >> 5;
  #pragma unroll
  for (int i = ty; i < 32; i += 8) t[i][tx] = in[(size_t)(rb + i) * C + cb + tx];
  __syncthreads();
  #pragma unroll
  for (int i = ty; i < 32; i += 8) {
    int c = cb + i;
    if (perm) {
      int hq = c / 240, tt = c - hq * 240;
      int reg = tt / 80, d = tt - reg * 80;
      c = reg * 1280 + hq * 80 + d;
    }
    out[(size_t)c * R + rb + tx] = (_Float16)t[tx][i];
  }
}

// ================= 256x256 8-phase GEMM (qkv producer), permuted-N epilogue =================

#define MM(NLO, AF, BF) do {                                                                       \
    __builtin_amdgcn_s_setprio(1);                                                                 \
    _Pragma("unroll")                                                                              \
    for (int m_ = 0; m_ < 8; m_++) {                                                               \
      acc[m_][NLO]     = __builtin_amdgcn_mfma_f32_16x16x32_f16(AF[m_], BF[NLO],     acc[m_][NLO],     0, 0, 0); \
      acc[m_][NLO + 1] = __builtin_amdgcn_mfma_f32_16x16x32_f16(AF[m_], BF[NLO + 1], acc[m_][NLO + 1], 0, 0, 0); \
    }                                                                                              \
    __builtin_amdgcn_s_setprio(0);                                                                 \
  } while (0)

#define LDA(KT, KK, DST) do {                                                                      \
    const _Float16* bas_ = &smem[(size_t)((((KT) & 1) * 2) + wr) * 8192];                          \
    _Pragma("unroll")                                                                              \
    for (int m_ = 0; m_ < 8; m_++)                                                                 \
      DST[m_] = *(const f16x8*)&bas_[(m_ * 16 + ln) * 64 + (((((KK) * 4) + g) ^ chB) << 3)];       \
  } while (0)

#define LDB(KT, KK, DST) do {                                                                      \
    const _Float16* bas_ = &smem[32768 + (size_t)((((KT) & 1) * 2) + (wc >> 1)) * 8192];           \
    _Pragma("unroll")                                                                              \
    for (int n_ = 0; n_ < 4; n_++)                                                                 \
      DST[n_] = *(const f16x8*)&bas_[((wc & 1) * 64 + n_ * 16 + ln) * 64 + (((((KK) * 4) + g) ^ chB) << 3)]; \
  } while (0)

template<int M, int N, int K>
__global__ __launch_bounds__(512, 2) void k_gemm8(const _Float16* __restrict__ A, const _Float16* __restrict__ BT,
                                                  const float* __restrict__ bias,
                                                  _Float16* __restrict__ qo, _Float16* __restrict__ ko,
                                                  _Float16* __restrict__ vo) {
  extern __shared__ _Float16 smem[];
  constexpr int NT = K / 64;
  constexpr int NI = NT / 2;
  const int tid = threadIdx.x;
  const int w = tid >> 6, lane = tid & 63, ln = lane & 15, g = lane >> 4;
  const int wr = w >> 2, wc = w & 3;
  const int l8 = lane >> 3, l7 = lane & 7;
  const int stChunk = (l7 ^ l8) << 3;
  const int chB = ln & 7;

  constexpr int MT = M / 256;
  const int xcd = blockIdx.x & 7;
  const int i = blockIdx.x >> 3;
  const int bm0 = (xcd * (MT / 8) + (i & 3)) * 256;
  const int bn0 = (i >> 2) * 256;

  auto stgA = [&](int kt, int hh) {
    _Float16* ldsb = &smem[(size_t)((kt & 1) * 2 + hh) * 8192 + w * 1024];
    const _Float16* g0 = &A[(size_t)(bm0 + hh * 128 + w * 16 + l8) * K + kt * 64 + stChunk];
    gl16(g0, ldsb);
    gl16(g0 + (size_t)8 * K, ldsb + 512);
  };
  auto stgB = [&](int kt, int hh) {
    _Float16* ldsb = &smem[32768 + (size_t)((kt & 1) * 2 + hh) * 8192 + w * 1024];
    const _Float16* g0 = &BT[(size_t)(bn0 + hh * 128 + w * 16 + l8) * K + kt * 64 + stChunk];
    gl16(g0, ldsb);
    gl16(g0 + (size_t)8 * K, ldsb + 512);
  };

  f32x4 acc[8][4] = {};
  f16x8 a0[8], a1[8], b0[4], b1[4];

  stgB(0, 0); stgB(0, 1); stgA(0, 0); stgA(0, 1);
  stgB(1, 0); stgB(1, 1); stgA(1, 0);
  VMCNT(6);
  BARRIER();
  LDA(0, 0, a0); LDB(0, 0, b0);

  for (int it = 0; it < NI; ++it) {
    const int T0 = 2 * it, T1 = 2 * it + 1;
    const int S0 = (T0 + 2 < NT) ? T0 + 2 : 0;
    const int S1 = (T1 + 2 < NT) ? T1 + 2 : 1;
    LDB(T0, 1, b1);
    stgA(T1, 1);
    BARRIER();
    MM(0, a0, b0);
    LGKM0(); BARRIER();
    LDA(T0, 1, a1);
    stgB(S0, 0);
    BARRIER();
    MM(2, a0, b0);
    LGKM0(); BARRIER();
    stgB(S0, 1);
    BARRIER();
    MM(0, a1, b1);
    VMCNT(4);
    LGKM0(); BARRIER();
    LDA(T1, 0, a0); LDB(T1, 0, b0);
    stgA(S0, 0);
    BARRIER();
    MM(2, a1, b1);
    LGKM0(); BARRIER();
    LDB(T1, 1, b1);
    stgA(S0, 1);
    BARRIER();
    MM(0, a0, b0);
    LGKM0(); BARRIER();
    LDA(T1, 1, a1);
    stgB(S1, 0);
    BARRIER();
    MM(2, a0, b0);
    LGKM0(); BARRIER();
    stgB(S1, 1);
    BARRIER();
    MM(0, a1, b1);
    VMCNT(4);
    LGKM0(); BARRIER();
    LDA(S0, 0, a0); LDB(S0, 0, b0);
    stgA(S1, 0);
    BARRIER();
    MM(2, a1, b1);
    LGKM0(); BARRIER();
  }

  // ---- epilogue: acc -> LDS f16 [256][256]; tile is purely q, k, or v ----
  VMCNT(0);
  BARRIER();
  _Float16* sH = smem;
  const int regn = bn0 / 1280;   // 0=q, 1=k, 2=v
  #pragma unroll
  for (int n = 0; n < 4; n++) {
    int col = wc * 64 + n * 16 + ln;
    int rel = bn0 - regn * 1280 + col;
    int h = rel / 80, d = rel - h * 80;
    float bv = bias[h * 240 + regn * 80 + d];
    float scl = (regn == 0) ? (0.11180339887498948f * 1.4426950408889634f) : 1.0f;
    #pragma unroll
    for (int m = 0; m < 8; m++) {
      #pragma unroll
      for (int r = 0; r < 4; r++) {
        int row = wr * 128 + m * 16 + 4 * g + r;
        sH[row * 256 + col] = (_Float16)((acc[m][n][r] + bv) * scl);
      }
    }
  }
  LGKM0();
  BARRIER();
  if (regn < 2) {
    _Float16* dst = regn ? ko : qo;   // [head][1024][80]
    #pragma unroll
    for (int i2 = 0; i2 < 16; i2++) {
      int id = tid + 512 * i2;
      int row = id >> 5, c8 = id & 31;
      f16x8 v = *(const f16x8*)&sH[row * 256 + c8 * 8];
      int rel = bn0 - regn * 1280 + c8 * 8;
      int h = rel / 80, d0 = rel - h * 80;
      int grow = bm0 + row;
      *(f16x8*)&dst[(size_t)(((grow & 7) * 16 + h) * 1024 + (grow >> 3)) * 80 + d0] = v;
    }
  } else {
    // v: write transposed directly -> vT[head][d][1024 s]
    #pragma unroll
    for (int t = 0; t < 16; t++) {
      int id = tid + 512 * t;
      int col = id & 255, rest = id >> 8;
      int hb = rest & 7, sch = rest >> 3;
      int rel = bn0 - 2560 + col;
      int h = rel / 80, d = rel - h * 80;
      f16x8 v;
      #pragma unroll
      for (int k = 0; k < 8; k++)
        v[k] = sH[(hb + 8 * (sch * 8 + k)) * 256 + col];
      *(f16x8*)&vo[(size_t)((hb * 16 + h) * 80 + d) * 1024 + (bm0 >> 3) + sch * 8] = v;
    }
  }
}

// ---------------- 128x128 GEMM (out_proj) ----------------
template<int M, int N, int K>
__global__ __launch_bounds__(256) void k_gemm(const _Float16* __restrict__ A, const _Float16* __restrict__ BT,
                                              const float* __restrict__ bias, float* __restrict__ outF) {
  __shared__ _Float16 Al[128 * 32];
  __shared__ _Float16 Bl[128 * 32];
  const int tid = threadIdx.x;
  const int w = tid >> 6, lane = tid & 63, ln = lane & 15, g = lane >> 4;
  const int bm0 = blockIdx.x * 128, bn0 = blockIdx.y * 128;
  const int wm = (w >> 1) * 64, wn = (w & 1) * 64;
  const int r0 = tid >> 2, c0 = (tid & 3) * 8;
  f32x4 acc[4][4] = {};
  for (int kt = 0; kt < K; kt += 32) {
    __syncthreads();
    gl16(&A[(size_t)(bm0 + r0) * K + kt + c0],      &Al[(w * 64) * 8]);
    gl16(&A[(size_t)(bm0 + r0 + 64) * K + kt + c0], &Al[(256 + w * 64) * 8]);
    gl16(&BT[(size_t)(bn0 + r0) * K + kt + c0],      &Bl[(w * 64) * 8]);
    gl16(&BT[(size_t)(bn0 + r0 + 64) * K + kt + c0], &Bl[(256 + w * 64) * 8]);
    __syncthreads();
    f16x8 af[4], bf[4];
    #pragma unroll
    for (int i = 0; i < 4; i++) af[i] = *(const f16x8*)&Al[(wm + i * 16 + ln) * 32 + g * 8];
    #pragma unroll
    for (int i = 0; i < 4; i++) bf[i] = *(const f16x8*)&Bl[(wn + i * 16 + ln) * 32 + g * 8];
    #pragma unroll
    for (int i = 0; i < 4; i++)
      #pragma unroll
      for (int j = 0; j < 4; j++)
        acc[i][j] = __builtin_amdgcn_mfma_f32_16x16x32_f16(af[i], bf[j], acc[i][j], 0, 0, 0);
  }
  #pragma unroll
  for (int j = 0; j < 4; j++) {
    int col = bn0 + wn + j * 16 + ln;
    float bv = bias[col];
    #pragma unroll
    for (int i = 0; i < 4; i++) {
      int mb = bm0 + wm + i * 16 + 4 * g;
      #pragma unroll
      for (int r = 0; r < 4; r++)
        outF[(size_t)(mb + r) * N + col] = acc[i][j][r] + bv;
    }
  }
}

// ---------------- flash attention: QBLK=256, 8 waves x 32 q-rows, in-register softmax ----------------
__global__ __launch_bounds__(512, 2) void k_attn(const _Float16* __restrict__ qb, const _Float16* __restrict__ kb,
                                                 const _Float16* __restrict__ vT, _Float16* __restrict__ ctxg) {
  extern __shared__ _Float16 smem[];
  _Float16* Kb0 = smem;                    // [64][128]
  _Float16* Kb1 = smem + 8192;
  _Float16* Vb0 = smem + 16384;            // [96][64]; rows 80..95 never written/stored
  _Float16* Vb1 = smem + 16384 + 6144;

  const int tid = threadIdx.x;
  const int w = tid >> 6, lane = tid & 63;
  const int l32 = lane & 31, h = lane >> 5;
  const int lx = l32 & 7;
  const int xcd = blockIdx.x & 7;
  const int j = blockIdx.x >> 3;
  const int head = xcd + 8 * (j & 15);
  const int s0 = (j >> 4) * 256;
  const int bb = head >> 4, h16 = head & 15;

  const int c1 = (tid < 128) ? tid + 512 : tid;
  const int kr0 = tid / 10, kh0 = tid - kr0 * 10;
  const int kr1 = c1 / 10,  kh1 = c1 - kr1 * 10;
  const int vr0 = tid >> 3, vh0 = tid & 7;
  const int vr1 = c1 >> 3,  vh1 = c1 & 7;
  const int kO0 = kr0 * 128 + ((kh0 ^ (kr0 & 7)) << 3);
  const int kO1 = kr1 * 128 + ((kh1 ^ (kr1 & 7)) << 3);
  const int vO0 = vr0 * 64 + ((vh0 ^ (vr0 & 7)) << 3);
  const int vO1 = vr1 * 64 + ((vh1 ^ (vr1 & 7)) << 3);
  const _Float16* kG0 = kb + (size_t)head * 81920 + kr0 * 80 + kh0 * 8;
  const _Float16* kG1 = kb + (size_t)head * 81920 + kr1 * 80 + kh1 * 8;
  const _Float16* vG0 = vT + (size_t)head * 81920 + vr0 * 1024 + vh0 * 8;
  const _Float16* vG1 = vT + (size_t)head * 81920 + vr1 * 1024 + vh1 * 8;

  uint4 krA, krB, vrA, vrB;
  auto issue = [&](int kt) {
    krA = *(const uint4*)(kG0 + kt * 5120);
    krB = *(const uint4*)(kG1 + kt * 5120);
    vrA = *(const uint4*)(vG0 + kt * 64);
    vrB = *(const uint4*)(vG1 + kt * 64);
  };
  auto stage = [&](int b) {
    _Float16* kd = b ? Kb1 : Kb0;
    _Float16* vd = b ? Vb1 : Vb0;
    *(uint4*)(kd + kO0) = krA;
    *(uint4*)(kd + kO1) = krB;
    *(uint4*)(vd + vO0) = vrA;
    *(uint4*)(vd + vO1) = vrB;
  };

  const int qrow = s0 + w * 32 + l32;
  f16x8 qf[5];
  #pragma unroll
  for (int s = 0; s < 5; s++)
    qf[s] = *(const f16x8*)&qb[(size_t)(head * 1024 + qrow) * 80 + s * 16 + h * 8];

  f32x16 ct[3] = {};
  float m_run = -INFINITY, l_run = 0.f;

  issue(0);
  stage(0);
  LGKM0();
  BARRIER();
  issue(1);

  for (int kt = 0; kt < 16; ++kt) {
    const _Float16* kc = (kt & 1) ? Kb1 : Kb0;
    const _Float16* vc = (kt & 1) ? Vb1 : Vb0;

    f32x16 sc0 = {}, sc1 = {};
    __builtin_amdgcn_s_setprio(1);
    #pragma unroll
    for (int s = 0; s < 5; ++s) {
      f16x8 kf0 = *(const f16x8*)&kc[l32 * 128 + (((2 * s + h) ^ lx) << 3)];
      f16x8 kf1 = *(const f16x8*)&kc[(32 + l32) * 128 + (((2 * s + h) ^ lx) << 3)];
      sc0 = __builtin_amdgcn_mfma_f32_32x32x16_f16(kf0, qf[s], sc0, 0, 0, 0);
      sc1 = __builtin_amdgcn_mfma_f32_32x32x16_f16(kf1, qf[s], sc1, 0, 0, 0);
    }
    __builtin_amdgcn_s_setprio(0);

    float mx[8];
    #pragma unroll
    for (int i = 0; i < 8; ++i)
      mx[i] = fmaxf(fmaxf(sc0[i], sc0[i + 8]), fmaxf(sc1[i], sc1[i + 8]));
    #pragma unroll
    for (int i = 0; i < 4; ++i) mx[i] = fmaxf(mx[i], mx[i + 4]);
    float tm = fmaxf(fmaxf(mx[0], mx[2]), fmaxf(mx[1], mx[3]));
    tm = fmaxf(tm, __shfl_xor(tm, 32));

    // T13 defer-rescale: only rescale when the running max grew by > 8 (exp2 domain)
    if (__any(tm > m_run + 8.f)) {
      float mnew = fmaxf(m_run, tm);
      float fac = exp2f(m_run - mnew);
      #pragma unroll
      for (int dt = 0; dt < 3; ++dt)
        #pragma unroll
        for (int i = 0; i < 16; ++i) ct[dt][i] *= fac;
      l_run *= fac;
      m_run = mnew;
    }

    float p0[16], p1[16];
    #pragma unroll
    for (int i = 0; i < 16; ++i) p0[i] = exp2f(sc0[i] - m_run);
    #pragma unroll
    for (int i = 0; i < 16; ++i) p1[i] = exp2f(sc1[i] - m_run);
    float ps = 0.f;
    #pragma unroll
    for (int i = 0; i < 16; ++i) ps += p0[i] + p1[i];

    unsigned fr[4][4];
    #define PACK4(T, PP) do {                                                \
        _Pragma("unroll")                                                    \
        for (int s16 = 0; s16 < 2; ++s16) {                                  \
          unsigned u0 = pk2(PP[8 * s16 + 0], PP[8 * s16 + 1]);               \
          unsigned u1 = pk2(PP[8 * s16 + 2], PP[8 * s16 + 3]);               \
          unsigned u2 = pk2(PP[8 * s16 + 4], PP[8 * s16 + 5]);               \
          unsigned u3 = pk2(PP[8 * s16 + 6], PP[8 * s16 + 7]);               \
          pl32swap(u0, u2); pl32swap(u1, u3);                                \
          fr[2 * (T) + s16][0] = u0; fr[2 * (T) + s16][1] = u1;              \
          fr[2 * (T) + s16][2] = u2; fr[2 * (T) + s16][3] = u3;              \
        }                                                                    \
      } while (0)
    PACK4(0, p0);
    PACK4(1, p1);

    l_run += ps + __shfl_xor(ps, 32);

    __builtin_amdgcn_s_setprio(1);
    #pragma unroll
    for (int ss = 0; ss < 4; ++ss) {
      u32x4 fu = { fr[ss][0], fr[ss][1], fr[ss][2], fr[ss][3] };
      f16x8 pf = __builtin_bit_cast(f16x8, fu);
      #pragma unroll
      for (int dt = 0; dt < 3; ++dt) {
        f16x8 vf = *(const f16x8*)&vc[(dt * 32 + l32) * 64 + (((2 * ss + h) ^ lx) << 3)];
        ct[dt] = __builtin_amdgcn_mfma_f32_32x32x16_f16(vf, pf, ct[dt], 0, 0, 0);
      }
    }
    __builtin_amdgcn_s_setprio(0);

    if (kt < 15) {
      stage((kt + 1) & 1);
      LGKM0();
      BARRIER();
      if (kt < 14) issue(kt + 2);
    }
  }

  float inv = 1.f / l_run;
  int sq = s0 + w * 32 + l32;
  _Float16* outp = ctxg + (size_t)(sq * 8 + bb) * 1280 + h16 * 80 + 4 * h;
  #pragma unroll
  for (int dt = 0; dt < 3; ++dt)
    #pragma unroll
    for (int rq = 0; rq < 4; ++rq) {
      if (dt == 2 && rq >= 2) continue;
      f16x4v o = { (_Float16)(ct[dt][rq * 4 + 0] * inv), (_Float16)(ct[dt][rq * 4 + 1] * inv),
                   (_Float16)(ct[dt][rq * 4 + 2] * inv), (_Float16)(ct[dt][rq * 4 + 3] * inv) };
      *(f16x4v*)&outp[dt * 32 + rq * 8] = o;
    }
}

extern "C" void kernel_launch(void* const* d_in, const int* in_sizes, int n_in,
                              void* d_out, int out_size, void* d_ws, size_t ws_size,
                              hipStream_t stream) {
  const float* x     = (const float*)d_in[0];
  const float* w_in  = (const float*)d_in[1];
  const float* b_in  = (const float*)d_in[2];
  const float* w_out = (const float*)d_in[3];
  const float* b_out = (const float*)d_in[4];
  float* out = (float*)d_out;

  char* ws = (char*)d_ws;
  size_t off = 0;
  auto carve = [&](size_t bytes) -> void* {
    void* p = ws + off;
    off += (bytes + 255) & ~(size_t)255;
    return p;
  };
  _Float16* xb     = (_Float16*)carve(8192ull * 1280 * 2);
  _Float16* w_inT  = (_Float16*)carve(3840ull * 1280 * 2);
  _Float16* w_outT = (_Float16*)carve(1280ull * 1280 * 2);
  _Float16* qb     = (_Float16*)carve(128ull * 1024 * 80 * 2);
  _Float16* kbuf   = (_Float16*)carve(128ull * 1024 * 80 * 2);
  _Float16* vT     = (_Float16*)carve(128ull * 1024 * 80 * 2);
  _Float16* ctxg   = (_Float16*)carve(8192ull * 1280 * 2);
  if (off > ws_size) return;

  hipFuncSetAttribute(reinterpret_cast<const void*>(&k_gemm8<8192, 3840, 1280>),
                      hipFuncAttributeMaxDynamicSharedMemorySize, 131072);
  hipFuncSetAttribute(reinterpret_cast<const void*>(&k_attn),
                      hipFuncAttributeMaxDynamicSharedMemorySize, 57344);

  k_prep<<<8448, 256, 0, stream>>>(x, xb, w_in, w_inT, w_out, w_outT);

  k_gemm8<8192, 3840, 1280><<<480, 512, 131072, stream>>>(xb, w_inT, b_in, qb, kbuf, vT);
  k_attn<<<512, 512, 57344, stream>>>(qb, kbuf, vT, ctxg);
  k_gemm<8192, 1280, 1280><<<dim3(64, 10), 256, 0, stream>>>(ctxg, w_outT, b_out, out);
}